// Round 1
// baseline (304.524 us; speedup 1.0000x reference)
//
#include <hip/hip_runtime.h>

// Problem constants (from reference setup_inputs)
#define BB 2
#define HH 160
#define WW 192
#define DD 160
#define NN (HH * WW * DD)        // 4,915,200
#define TOTAL (BB * NN)          // 9,830,400  (divisible by 256: 38400 blocks)

__global__ __launch_bounds__(256)
void SpatialDeformer3D_kernel(const float* __restrict__ X,
                              const float* __restrict__ def,
                              float* __restrict__ out) {
    const int n = blockIdx.x * 256 + threadIdx.x;   // TOTAL is an exact multiple of 256

    // decompose n -> (b, h, w, d); divisions by constants become magic-muls
    const int b    = n / NN;
    const int rem  = n - b * NN;
    const int h    = rem / (WW * DD);
    const int rem2 = rem - h * (WW * DD);
    const int w    = rem2 / DD;
    const int d    = rem2 - w * DD;

    // deformation: 3 consecutive floats per voxel (coalesced across the wave)
    const float* dp = def + (size_t)n * 3;
    const float x = (float)w + dp[0];
    const float y = (float)h + dp[1];
    const float z = (float)d + dp[2];

    int ix0 = (int)floorf(x);
    int iy0 = (int)floorf(y);
    int iz0 = (int)floorf(z);
    int ix1 = ix0 + 1, iy1 = iy0 + 1, iz1 = iz0 + 1;
    ix0 = min(max(ix0, 0), WW - 1); ix1 = min(max(ix1, 0), WW - 1);
    iy0 = min(max(iy0, 0), HH - 1); iy1 = min(max(iy1, 0), HH - 1);
    iz0 = min(max(iz0, 0), DD - 1); iz1 = min(max(iz1, 0), DD - 1);

    // weights use CLIPPED corner coords vs UNCLIPPED continuous coords (reference semantics)
    const float x0f = (float)ix0, x1f = (float)ix1;
    const float y0f = (float)iy0, y1f = (float)iy1;
    const float z0f = (float)iz0, z1f = (float)iz1;

    const float wx0 = x1f - x, wx1 = x - x0f;
    const float wy0 = y1f - y, wy1 = y - y0f;
    const float wz0 = z1f - z, wz1 = z - z0f;

    // gather channel 0 of X (interleaved 2-channel layout -> index * 2)
    const float* Xb = X + (size_t)b * (2u * (size_t)NN);
    const int ry0 = iy0 * (WW * DD), ry1 = iy1 * (WW * DD);
    const int rx0 = ix0 * DD,        rx1 = ix1 * DD;

    const float p000 = Xb[(size_t)(ry0 + rx0 + iz0) * 2];
    const float p001 = Xb[(size_t)(ry0 + rx0 + iz1) * 2];
    const float p010 = Xb[(size_t)(ry0 + rx1 + iz0) * 2];
    const float p011 = Xb[(size_t)(ry0 + rx1 + iz1) * 2];
    const float p100 = Xb[(size_t)(ry1 + rx0 + iz0) * 2];
    const float p101 = Xb[(size_t)(ry1 + rx0 + iz1) * 2];
    const float p110 = Xb[(size_t)(ry1 + rx1 + iz0) * 2];
    const float p111 = Xb[(size_t)(ry1 + rx1 + iz1) * 2];

    const float r =
        wy0 * (wx0 * (wz0 * p000 + wz1 * p001) + wx1 * (wz0 * p010 + wz1 * p011)) +
        wy1 * (wx0 * (wz0 * p100 + wz1 * p101) + wx1 * (wz0 * p110 + wz1 * p111));

    out[n] = r;
}

extern "C" void kernel_launch(void* const* d_in, const int* in_sizes, int n_in,
                              void* d_out, int out_size, void* d_ws, size_t ws_size,
                              hipStream_t stream) {
    const float* X   = (const float*)d_in[0];
    const float* def = (const float*)d_in[1];
    float* out = (float*)d_out;

    const int blocks = TOTAL / 256;   // 38400
    SpatialDeformer3D_kernel<<<blocks, 256, 0, stream>>>(X, def, out);
}

// Round 2
// 279.214 us; speedup vs baseline: 1.0906x; 1.0906x over previous
//
#include <hip/hip_runtime.h>

// Problem constants (from reference setup_inputs)
#define BB 2
#define HH 160
#define WW 192
#define DD 160
#define NN (HH * WW * DD)        // 4,915,200
#define TOTAL (BB * NN)          // 9,830,400  (divisible by 1024)

// 8-byte vector with 4-byte alignment: gfx950 supports unaligned global
// dwordx2 loads in HW, so the compiler emits global_load_dwordx2 even at
// align(4). This is what lets one load fetch the (z0, z0+1) corner pair.
struct __attribute__((packed, aligned(4))) f2u { float lo, hi; };

// Pass 1: compact channel 0 of X (interleaved (...,2)) into contiguous C.
// Each thread handles 4 voxels: two aligned float4 reads -> one float4 write.
__global__ __launch_bounds__(256)
void compact_ch0_kernel(const float4* __restrict__ X4, float4* __restrict__ C4) {
    const int i = blockIdx.x * 256 + threadIdx.x;   // i in [0, TOTAL/4)
    const float4 a = X4[2 * i];       // voxels 4i, 4i+1 (ch0 at .x, .z)
    const float4 b = X4[2 * i + 1];   // voxels 4i+2, 4i+3
    C4[i] = make_float4(a.x, a.z, b.x, b.z);
}

// Pass 2: trilinear gather from compacted C. 4 dwordx2 gathers per voxel
// (z-pair fused), halving divergent address count vs the naive 8.
__global__ __launch_bounds__(256)
void SpatialDeformer3D_kernel(const float* __restrict__ C,
                              const float* __restrict__ def,
                              float* __restrict__ out) {
    const int n = blockIdx.x * 256 + threadIdx.x;

    const int b    = n / NN;
    const int rem  = n - b * NN;
    const int h    = rem / (WW * DD);
    const int rem2 = rem - h * (WW * DD);
    const int w    = rem2 / DD;
    const int d    = rem2 - w * DD;

    const float* dp = def + (size_t)n * 3;
    const float x = (float)w + dp[0];
    const float y = (float)h + dp[1];
    const float z = (float)d + dp[2];

    int ix0 = (int)floorf(x);
    int iy0 = (int)floorf(y);
    int iz0 = (int)floorf(z);
    int ix1 = ix0 + 1, iy1 = iy0 + 1;
    ix0 = min(max(ix0, 0), WW - 1); ix1 = min(max(ix1, 0), WW - 1);
    iy0 = min(max(iy0, 0), HH - 1); iy1 = min(max(iy1, 0), HH - 1);
    const int czlo = min(max(iz0, 0), DD - 1);       // clipped z0
    const int czhi = min(max(iz0 + 1, 0), DD - 1);   // clipped z1
    const int zb   = min(max(iz0, 0), DD - 2);       // load base (zb, zb+1 in-range)

    // weights from CLIPPED corners vs UNCLIPPED continuous coords (reference semantics)
    const float wx0 = (float)ix1 - x, wx1 = x - (float)ix0;
    const float wy0 = (float)iy1 - y, wy1 = y - (float)iy0;
    const float wz0 = (float)czhi - z, wz1 = z - (float)czlo;

    // z-pair selection masks (shared by all 4 rows):
    // czlo in {zb, zb+1}; czhi in {zb, zb+1}
    const bool lo_is_v0 = (czlo == zb);
    const bool hi_is_v1 = (czhi == zb + 1);

    const float* Cb = C + (size_t)b * NN;
    const int r00 = iy0 * (WW * DD) + ix0 * DD + zb;
    const int r01 = iy0 * (WW * DD) + ix1 * DD + zb;
    const int r10 = iy1 * (WW * DD) + ix0 * DD + zb;
    const int r11 = iy1 * (WW * DD) + ix1 * DD + zb;

    const f2u v00 = *(const f2u*)(Cb + r00);
    const f2u v01 = *(const f2u*)(Cb + r01);
    const f2u v10 = *(const f2u*)(Cb + r10);
    const f2u v11 = *(const f2u*)(Cb + r11);

    const float p000 = lo_is_v0 ? v00.lo : v00.hi;   // (y0,x0,z0)
    const float p001 = hi_is_v1 ? v00.hi : v00.lo;   // (y0,x0,z1)
    const float p010 = lo_is_v0 ? v01.lo : v01.hi;   // (y0,x1,z0)
    const float p011 = hi_is_v1 ? v01.hi : v01.lo;   // (y0,x1,z1)
    const float p100 = lo_is_v0 ? v10.lo : v10.hi;   // (y1,x0,z0)
    const float p101 = hi_is_v1 ? v10.hi : v10.lo;   // (y1,x0,z1)
    const float p110 = lo_is_v0 ? v11.lo : v11.hi;   // (y1,x1,z0)
    const float p111 = hi_is_v1 ? v11.hi : v11.lo;   // (y1,x1,z1)

    const float r =
        wy0 * (wx0 * (wz0 * p000 + wz1 * p001) + wx1 * (wz0 * p010 + wz1 * p011)) +
        wy1 * (wx0 * (wz0 * p100 + wz1 * p101) + wx1 * (wz0 * p110 + wz1 * p111));

    out[n] = r;
}

// Fallback (R1 kernel): direct gather from interleaved X, used only if the
// workspace is too small to hold the compacted channel (39.3 MB).
__global__ __launch_bounds__(256)
void SpatialDeformer3D_direct_kernel(const float* __restrict__ X,
                                     const float* __restrict__ def,
                                     float* __restrict__ out) {
    const int n = blockIdx.x * 256 + threadIdx.x;

    const int b    = n / NN;
    const int rem  = n - b * NN;
    const int h    = rem / (WW * DD);
    const int rem2 = rem - h * (WW * DD);
    const int w    = rem2 / DD;
    const int d    = rem2 - w * DD;

    const float* dp = def + (size_t)n * 3;
    const float x = (float)w + dp[0];
    const float y = (float)h + dp[1];
    const float z = (float)d + dp[2];

    int ix0 = (int)floorf(x);
    int iy0 = (int)floorf(y);
    int iz0 = (int)floorf(z);
    int ix1 = ix0 + 1, iy1 = iy0 + 1, iz1 = iz0 + 1;
    ix0 = min(max(ix0, 0), WW - 1); ix1 = min(max(ix1, 0), WW - 1);
    iy0 = min(max(iy0, 0), HH - 1); iy1 = min(max(iy1, 0), HH - 1);
    iz0 = min(max(iz0, 0), DD - 1); iz1 = min(max(iz1, 0), DD - 1);

    const float wx0 = (float)ix1 - x, wx1 = x - (float)ix0;
    const float wy0 = (float)iy1 - y, wy1 = y - (float)iy0;
    const float wz0 = (float)iz1 - z, wz1 = z - (float)iz0;

    const float* Xb = X + (size_t)b * (2u * (size_t)NN);
    const int ry0 = iy0 * (WW * DD), ry1 = iy1 * (WW * DD);
    const int rx0 = ix0 * DD,        rx1 = ix1 * DD;

    const float p000 = Xb[(size_t)(ry0 + rx0 + iz0) * 2];
    const float p001 = Xb[(size_t)(ry0 + rx0 + iz1) * 2];
    const float p010 = Xb[(size_t)(ry0 + rx1 + iz0) * 2];
    const float p011 = Xb[(size_t)(ry0 + rx1 + iz1) * 2];
    const float p100 = Xb[(size_t)(ry1 + rx0 + iz0) * 2];
    const float p101 = Xb[(size_t)(ry1 + rx0 + iz1) * 2];
    const float p110 = Xb[(size_t)(ry1 + rx1 + iz0) * 2];
    const float p111 = Xb[(size_t)(ry1 + rx1 + iz1) * 2];

    const float r =
        wy0 * (wx0 * (wz0 * p000 + wz1 * p001) + wx1 * (wz0 * p010 + wz1 * p011)) +
        wy1 * (wx0 * (wz0 * p100 + wz1 * p101) + wx1 * (wz0 * p110 + wz1 * p111));

    out[n] = r;
}

extern "C" void kernel_launch(void* const* d_in, const int* in_sizes, int n_in,
                              void* d_out, int out_size, void* d_ws, size_t ws_size,
                              hipStream_t stream) {
    const float* X   = (const float*)d_in[0];
    const float* def = (const float*)d_in[1];
    float* out = (float*)d_out;

    const size_t need = (size_t)TOTAL * sizeof(float);   // 39.3 MB compacted ch0
    if (ws_size >= need) {
        float* C = (float*)d_ws;
        compact_ch0_kernel<<<TOTAL / 4 / 256, 256, 0, stream>>>(
            (const float4*)X, (float4*)C);
        SpatialDeformer3D_kernel<<<TOTAL / 256, 256, 0, stream>>>(C, def, out);
    } else {
        SpatialDeformer3D_direct_kernel<<<TOTAL / 256, 256, 0, stream>>>(X, def, out);
    }
}